// Round 1
// baseline (40.445 us; speedup 1.0000x reference)
//
#include <hip/hip_runtime.h>

#define NQ 4
#define NL 4

// ---------------------------------------------------------------------------
// Precompute kernel: build V[16][16][2] = U * diag((-i)^popcount(k)),
// where U is the full 4-layer StronglyEntanglingLayers unitary (Rot + CNOT
// ring). One wave; threads 0..15 each push basis column k through the gates.
// ---------------------------------------------------------------------------
__global__ __launch_bounds__(64) void qnn_precompute(
    const float* __restrict__ w,   // [4][4][3] (phi, theta, omega)
    float* __restrict__ V)         // [16][16][2] interleaved (re, im)
{
  int k = threadIdx.x;
  if (k >= 16) return;
  float pr[16], pi[16];
#pragma unroll
  for (int j = 0; j < 16; ++j) { pr[j] = (j == k) ? 1.f : 0.f; pi[j] = 0.f; }

  const int ranges[4] = {1, 2, 3, 1};   // (l % (NQ-1)) + 1
#pragma unroll
  for (int l = 0; l < NL; ++l) {
    // Rot(phi,theta,omega) on each wire
#pragma unroll
    for (int q = 0; q < NQ; ++q) {
      float phi = w[l*12 + q*3 + 0];
      float th  = w[l*12 + q*3 + 1];
      float om  = w[l*12 + q*3 + 2];
      float st, ct;  __sincosf(0.5f*th, &st, &ct);
      float spo, cpo; __sincosf(0.5f*(phi+om), &spo, &cpo);
      float smo, cmo; __sincosf(0.5f*(phi-om), &smo, &cmo);
      // Rot = [[epo*c, -emo*s],[conj(emo)*s, conj(epo)*c]]
      // epo = cpo - i spo ; emo = cmo + i smo
      float ar = cpo*ct,  ai = -spo*ct;
      float br = -cmo*st, bi = -smo*st;
      float dr = cmo*st,  di = -smo*st;
      float er = cpo*ct,  ei = spo*ct;
      int m = 8 >> q;      // wire q <-> bit (3-q)
#pragma unroll
      for (int i0 = 0; i0 < 16; ++i0) {
        if (i0 & m) continue;
        int i1 = i0 | m;
        float x0r = pr[i0], x0i = pi[i0], x1r = pr[i1], x1i = pi[i1];
        pr[i0] = ar*x0r - ai*x0i + br*x1r - bi*x1i;
        pi[i0] = ar*x0i + ai*x0r + br*x1i + bi*x1r;
        pr[i1] = dr*x0r - di*x0i + er*x1r - ei*x1i;
        pi[i1] = dr*x0i + di*x0r + er*x1i + ei*x1r;
      }
    }
    // ring of CNOTs: control q, target (q+r)%4, applied in order
    int r = ranges[l];
#pragma unroll
    for (int q = 0; q < NQ; ++q) {
      int mc = 8 >> q;
      int mt = 8 >> ((q + r) & 3);
#pragma unroll
      for (int i = 0; i < 16; ++i) {
        if ((i & mc) && !(i & mt)) {
          int i2 = i | mt;
          float tr = pr[i]; pr[i] = pr[i2]; pr[i2] = tr;
          float ti = pi[i]; pi[i] = pi[i2]; pi[i2] = ti;
        }
      }
    }
  }

  // fold (-i)^popcount(k) into column k, write out
  int pc = __popc(k) & 3;
#pragma unroll
  for (int j = 0; j < 16; ++j) {
    float re = pr[j], im = pi[j], re2, im2;
    if      (pc == 0) { re2 =  re; im2 =  im; }
    else if (pc == 1) { re2 =  im; im2 = -re; }
    else if (pc == 2) { re2 = -re; im2 = -im; }
    else              { re2 = -im; im2 =  re; }
    V[(j*16 + k)*2 + 0] = re2;
    V[(j*16 + k)*2 + 1] = im2;
  }
}

// ---------------------------------------------------------------------------
// Main kernel: 1 thread = 1 sample.
//   r[16] = real RX tensor-product magnitudes
//   psi   = V * r   (complex 16x16 * real 16-vec, 512 FMA)
//   z[w]  = signed prob sums, out = fc_w @ z + fc_b
// Output staged via LDS for coalesced stores.
// ---------------------------------------------------------------------------
__global__ __launch_bounds__(256) void qnn_main(
    const float4* __restrict__ x,     // [B] of float4  (B,4)
    const float*  __restrict__ V,     // [16][16][2]
    const float*  __restrict__ fcw,   // [10][4]
    const float*  __restrict__ fcb,   // [10]
    float*        __restrict__ out,   // [B*10]
    int nB)
{
  __shared__ float so[256 * 11];      // stride-11 pad: 2-way max on write
  int t = threadIdx.x;
  int b = blockIdx.x * 256 + t;

  if (b < nB) {
    float4 xv = x[b];
    float s0, c0, s1, c1, s2, c2, s3, c3;
    __sincosf(0.5f * xv.x, &s0, &c0);
    __sincosf(0.5f * xv.y, &s1, &c1);
    __sincosf(0.5f * xv.z, &s2, &c2);
    __sincosf(0.5f * xv.w, &s3, &c3);

    // r[k], k = w0*8 + w1*4 + w2*2 + w3, bit set -> sin
    float r[16];
    {
      float w01[4];
      w01[0] = c0 * c1; w01[1] = c0 * s1; w01[2] = s0 * c1; w01[3] = s0 * s1;
      float w012[8];
#pragma unroll
      for (int i = 0; i < 4; ++i) {
        w012[2*i]   = w01[i] * c2;
        w012[2*i+1] = w01[i] * s2;
      }
#pragma unroll
      for (int i = 0; i < 8; ++i) {
        r[2*i]   = w012[i] * c3;
        r[2*i+1] = w012[i] * s3;
      }
    }

    float z0 = 0.f, z1 = 0.f, z2 = 0.f, z3 = 0.f;
#pragma unroll
    for (int j = 0; j < 16; ++j) {
      float re = 0.f, im = 0.f;
#pragma unroll
      for (int k = 0; k < 16; ++k) {
        re = fmaf(V[(j*16 + k)*2 + 0], r[k], re);
        im = fmaf(V[(j*16 + k)*2 + 1], r[k], im);
      }
      float p = fmaf(re, re, im * im);
      z0 += (j & 8) ? -p : p;
      z1 += (j & 4) ? -p : p;
      z2 += (j & 2) ? -p : p;
      z3 += (j & 1) ? -p : p;
    }

#pragma unroll
    for (int o = 0; o < 10; ++o) {
      float v = fcb[o];
      v = fmaf(fcw[o*4 + 0], z0, v);
      v = fmaf(fcw[o*4 + 1], z1, v);
      v = fmaf(fcw[o*4 + 2], z2, v);
      v = fmaf(fcw[o*4 + 3], z3, v);
      so[t * 11 + o] = v;
    }
  }
  __syncthreads();

  // coalesced write of this block's 2560 output floats
  int base = blockIdx.x * 2560;
  int lim  = nB * 10;
#pragma unroll
  for (int i = 0; i < 10; ++i) {
    int f = t + i * 256;
    int g = base + f;
    if (g < lim) {
      int s = f / 10;
      int o = f - s * 10;
      out[g] = so[s * 11 + o];
    }
  }
}

extern "C" void kernel_launch(void* const* d_in, const int* in_sizes, int n_in,
                              void* d_out, int out_size, void* d_ws, size_t ws_size,
                              hipStream_t stream) {
  const float* x   = (const float*)d_in[0];
  const float* w   = (const float*)d_in[1];
  const float* fcw = (const float*)d_in[2];
  const float* fcb = (const float*)d_in[3];
  float* out = (float*)d_out;
  float* V   = (float*)d_ws;        // 16*16*2 floats = 2 KB
  int nB = in_sizes[0] / 4;

  hipLaunchKernelGGL(qnn_precompute, dim3(1), dim3(64), 0, stream, w, V);
  int nblk = (nB + 255) / 256;
  hipLaunchKernelGGL(qnn_main, dim3(nblk), dim3(256), 0, stream,
                     (const float4*)x, V, fcw, fcb, out, nB);
}

// Round 2
// 39.198 us; speedup vs baseline: 1.0318x; 1.0318x over previous
//
#include <hip/hip_runtime.h>

#define NQ 4
#define NL 4

// ---------------------------------------------------------------------------
// Precompute kernel (unchanged, verified R0): build
// V[16][16][2] = U * diag((-i)^popcount(k)), U = full SEL unitary.
// ---------------------------------------------------------------------------
__global__ __launch_bounds__(64) void qnn_precompute(
    const float* __restrict__ w,   // [4][4][3] (phi, theta, omega)
    float* __restrict__ V)         // [16][16][2] interleaved (re, im)
{
  int k = threadIdx.x;
  if (k >= 16) return;
  float pr[16], pi[16];
#pragma unroll
  for (int j = 0; j < 16; ++j) { pr[j] = (j == k) ? 1.f : 0.f; pi[j] = 0.f; }

  const int ranges[4] = {1, 2, 3, 1};
#pragma unroll
  for (int l = 0; l < NL; ++l) {
#pragma unroll
    for (int q = 0; q < NQ; ++q) {
      float phi = w[l*12 + q*3 + 0];
      float th  = w[l*12 + q*3 + 1];
      float om  = w[l*12 + q*3 + 2];
      float st, ct;  __sincosf(0.5f*th, &st, &ct);
      float spo, cpo; __sincosf(0.5f*(phi+om), &spo, &cpo);
      float smo, cmo; __sincosf(0.5f*(phi-om), &smo, &cmo);
      float ar = cpo*ct,  ai = -spo*ct;
      float br = -cmo*st, bi = -smo*st;
      float dr = cmo*st,  di = -smo*st;
      float er = cpo*ct,  ei = spo*ct;
      int m = 8 >> q;
#pragma unroll
      for (int i0 = 0; i0 < 16; ++i0) {
        if (i0 & m) continue;
        int i1 = i0 | m;
        float x0r = pr[i0], x0i = pi[i0], x1r = pr[i1], x1i = pi[i1];
        pr[i0] = ar*x0r - ai*x0i + br*x1r - bi*x1i;
        pi[i0] = ar*x0i + ai*x0r + br*x1i + bi*x1r;
        pr[i1] = dr*x0r - di*x0i + er*x1r - ei*x1i;
        pi[i1] = dr*x0i + di*x0r + er*x1i + ei*x1r;
      }
    }
    int r = ranges[l];
#pragma unroll
    for (int q = 0; q < NQ; ++q) {
      int mc = 8 >> q;
      int mt = 8 >> ((q + r) & 3);
#pragma unroll
      for (int i = 0; i < 16; ++i) {
        if ((i & mc) && !(i & mt)) {
          int i2 = i | mt;
          float tr = pr[i]; pr[i] = pr[i2]; pr[i2] = tr;
          float ti = pi[i]; pi[i] = pi[i2]; pi[i2] = ti;
        }
      }
    }
  }

  int pc = __popc(k) & 3;
#pragma unroll
  for (int j = 0; j < 16; ++j) {
    float re = pr[j], im = pi[j], re2, im2;
    if      (pc == 0) { re2 =  re; im2 =  im; }
    else if (pc == 1) { re2 =  im; im2 = -re; }
    else if (pc == 2) { re2 = -re; im2 = -im; }
    else              { re2 = -im; im2 =  re; }
    V[(j*16 + k)*2 + 0] = re2;
    V[(j*16 + k)*2 + 1] = im2;
  }
}

// ---------------------------------------------------------------------------
// Main kernel: V staged in LDS (2 KB), read per-row with 8 uniform-address
// ds_read_b128 (broadcast). 2 samples per thread to amortize LDS issue cost.
// ---------------------------------------------------------------------------
__global__ __launch_bounds__(256, 4) void qnn_main(
    const float4* __restrict__ x,     // [B] of float4  (B,4)
    const float4* __restrict__ V4,    // [16][16][2] as float4[128]
    const float*  __restrict__ fcw,   // [10][4]
    const float*  __restrict__ fcb,   // [10]
    float*        __restrict__ out,   // [B*10]
    int nB)
{
  __shared__ float sV[512];           // 2 KB
  __shared__ float so[512 * 11];      // 22.5 KB, stride-11 pad

  int t = threadIdx.x;
  if (t < 128) ((float4*)sV)[t] = V4[t];
  __syncthreads();

  int base = blockIdx.x * 512;

  float r[2][16];
  float zz[2][4] = {{0.f,0.f,0.f,0.f},{0.f,0.f,0.f,0.f}};

#pragma unroll
  for (int s = 0; s < 2; ++s) {
    int b = base + t + s * 256;
    float4 xv = (b < nB) ? x[b] : make_float4(0.f, 0.f, 0.f, 0.f);
    float s0, c0, s1, c1, s2, c2, s3, c3;
    __sincosf(0.5f * xv.x, &s0, &c0);
    __sincosf(0.5f * xv.y, &s1, &c1);
    __sincosf(0.5f * xv.z, &s2, &c2);
    __sincosf(0.5f * xv.w, &s3, &c3);
    float w01[4];
    w01[0] = c0 * c1; w01[1] = c0 * s1; w01[2] = s0 * c1; w01[3] = s0 * s1;
#pragma unroll
    for (int i = 0; i < 4; ++i) {
      float a = w01[i] * c2, bb = w01[i] * s2;
      r[s][4*i + 0] = a  * c3;
      r[s][4*i + 1] = a  * s3;
      r[s][4*i + 2] = bb * c3;
      r[s][4*i + 3] = bb * s3;
    }
  }

#pragma unroll
  for (int j = 0; j < 16; ++j) {
    // row j of V: 32 floats, uniform address -> broadcast ds_read_b128 x8
    float vv[32];
#pragma unroll
    for (int q = 0; q < 8; ++q) {
      float4 qv = *(const float4*)(sV + j * 32 + q * 4);
      vv[4*q + 0] = qv.x; vv[4*q + 1] = qv.y;
      vv[4*q + 2] = qv.z; vv[4*q + 3] = qv.w;
    }
#pragma unroll
    for (int s = 0; s < 2; ++s) {
      float re = 0.f, im = 0.f;
#pragma unroll
      for (int k = 0; k < 16; ++k) {
        re = fmaf(vv[2*k + 0], r[s][k], re);
        im = fmaf(vv[2*k + 1], r[s][k], im);
      }
      float p = fmaf(re, re, im * im);
      zz[s][0] += (j & 8) ? -p : p;
      zz[s][1] += (j & 4) ? -p : p;
      zz[s][2] += (j & 2) ? -p : p;
      zz[s][3] += (j & 1) ? -p : p;
    }
  }

#pragma unroll
  for (int s = 0; s < 2; ++s) {
    int sl = t + s * 256;
#pragma unroll
    for (int o = 0; o < 10; ++o) {
      float v = fcb[o];
      v = fmaf(fcw[o*4 + 0], zz[s][0], v);
      v = fmaf(fcw[o*4 + 1], zz[s][1], v);
      v = fmaf(fcw[o*4 + 2], zz[s][2], v);
      v = fmaf(fcw[o*4 + 3], zz[s][3], v);
      so[sl * 11 + o] = v;
    }
  }
  __syncthreads();

  // coalesced write of this block's 5120 output floats
  int gbase = blockIdx.x * 5120;
  int lim   = nB * 10;
#pragma unroll
  for (int i = 0; i < 20; ++i) {
    int f = t + i * 256;
    int g = gbase + f;
    if (g < lim) {
      int s = f / 10;
      int o = f - s * 10;
      out[g] = so[s * 11 + o];
    }
  }
}

extern "C" void kernel_launch(void* const* d_in, const int* in_sizes, int n_in,
                              void* d_out, int out_size, void* d_ws, size_t ws_size,
                              hipStream_t stream) {
  const float* x   = (const float*)d_in[0];
  const float* w   = (const float*)d_in[1];
  const float* fcw = (const float*)d_in[2];
  const float* fcb = (const float*)d_in[3];
  float* out = (float*)d_out;
  float* V   = (float*)d_ws;        // 16*16*2 floats = 2 KB
  int nB = in_sizes[0] / 4;

  hipLaunchKernelGGL(qnn_precompute, dim3(1), dim3(64), 0, stream, w, V);
  int nblk = (nB + 511) / 512;
  hipLaunchKernelGGL(qnn_main, dim3(nblk), dim3(256), 0, stream,
                     (const float4*)x, (const float4*)V, fcw, fcb, out, nB);
}